// Round 3
// baseline (615.090 us; speedup 1.0000x reference)
//
#include <hip/hip_runtime.h>
#include <hip/hip_bf16.h>
#include <cstdint>
#include <cstddef>

// ---------------- problem constants ----------------
#define M_TOK 4096          // B*S = 4*1024 tokens
#define HID   1024
#define NHEAD 16002
#define NHEAD_PAD 16128     // 126*128
#define P0    256
#define N0    12000
#define N0_PAD 12032        // 94*128
#define P1    64
#define P1_PAD 128
#define N1    8000
#define N1_PAD 8064         // 63*128

typedef __bf16 bf16_t;
typedef __bf16 bf16x8 __attribute__((ext_vector_type(8)));
typedef __bf16 bf16x4 __attribute__((ext_vector_type(4)));
typedef float  f32x4  __attribute__((ext_vector_type(4)));

// async global->LDS, 16B per lane. lds ptr must be wave-uniform base;
// HW writes base + lane*16 (m104/m108 semantics).
__device__ __forceinline__ void load16(const bf16_t* g, bf16_t* l) {
    __builtin_amdgcn_global_load_lds(
        (__attribute__((address_space(1))) void*)g,
        (__attribute__((address_space(3))) void*)l,
        16, 0, 0);
}

// ---------------- cast inp f32 -> bf16 (vectorized x4) ----------------
__global__ void cast_kernel(const float* __restrict__ src, bf16_t* __restrict__ dst, int n4) {
    int i = blockIdx.x * blockDim.x + threadIdx.x;
    if (i < n4) {
        float4 v = reinterpret_cast<const float4*>(src)[i];
        bf16x4 o;
        o[0] = (bf16_t)v.x; o[1] = (bf16_t)v.y; o[2] = (bf16_t)v.z; o[3] = (bf16_t)v.w;
        reinterpret_cast<bf16x4*>(dst)[i] = o;
    }
}

// ---------------- tiled transpose with zero padding ----------------
// src: K x N (f32, row-major).  dst: Npad x Kpad (bf16, row-major), pad = 0.
// Tile: 32 n-cols x 64 k-rows; writes are bf16x8 (16B) fully coalesced.
__global__ void transpose_pad(const float* __restrict__ W, bf16_t* __restrict__ WT,
                              int K, int N, int Kpad, int Npad) {
    __shared__ float tile[64][33];
    int n0 = blockIdx.x * 32, k0 = blockIdx.y * 64;
    int tx = threadIdx.x & 31, ty = threadIdx.x >> 5;   // 32 x 8
    #pragma unroll
    for (int i = 0; i < 8; i++) {
        int k = k0 + ty + i * 8, n = n0 + tx;
        tile[ty + i * 8][tx] = (k < K && n < N) ? W[(size_t)k * N + n] : 0.0f;
    }
    __syncthreads();
    int n = threadIdx.x >> 3, kc = threadIdx.x & 7;     // n 0..31, kc 0..7
    bf16x8 v;
    #pragma unroll
    for (int j = 0; j < 8; j++) v[j] = (bf16_t)tile[kc * 8 + j][n];
    *reinterpret_cast<bf16x8*>(WT + (size_t)(n0 + n) * Kpad + k0 + kc * 8) = v;
}

// ---------------- init: zero accumulators + out, precompute targets ----------------
__global__ void init_kernel(const int* __restrict__ labels, float* __restrict__ acc6,
                            int* __restrict__ tgts, float* __restrict__ out) {
    int t = blockIdx.x * blockDim.x + threadIdx.x;   // 4096 threads
    for (int j = t; j < 6 * M_TOK; j += M_TOK) acc6[j] = 0.0f;
    if (t == 0) out[0] = 0.0f;
    int lbl = labels[t];
    tgts[t]             = (lbl < 16000) ? lbl : ((lbl < 28000) ? 16000 : 16001);
    int t0 = lbl - 16000; t0 = t0 < 0 ? 0 : (t0 > 11999 ? 11999 : t0);
    int t1 = lbl - 28000; t1 = t1 < 0 ? 0 : (t1 > 7999  ? 7999  : t1);
    tgts[M_TOK + t]     = t0;
    tgts[2 * M_TOK + t] = t1;
}

// ---------------- MFMA GEMM: C = A(M x K) * BT(Npad x K)^T ----------------
// Block tile 128x128, BK=32, 4 waves 2x2, each wave 64x64 via 4x4 mfma_f32_16x16x32_bf16.
// LDS layout is K-MAJOR: [plane j=0..3][row 0..127][8 bf16], plane j = k-offset j*8.
// Fragment read addr = (q*128 + row)*16B -> bank (row*4)%32 -> 2-way only (free, m136).
template <bool LSE>
__launch_bounds__(256, 2)
__global__ void gemm_kernel(const bf16_t* __restrict__ A, const bf16_t* __restrict__ BT,
                            const float* __restrict__ bias, int K, int Npad, int realN,
                            const int* __restrict__ tgt, float* __restrict__ sumexp,
                            float* __restrict__ lab, bf16_t* __restrict__ out) {
    __shared__ __align__(16) bf16_t As[4 * 128 * 8];
    __shared__ __align__(16) bf16_t Bs[4 * 128 * 8];

    const int tid  = threadIdx.x;
    const int lane = tid & 63;
    const int wave = tid >> 6;
    const int wm = wave >> 1, wn = wave & 1;
    const int q = lane >> 4, lrow = lane & 15;
    const int m0 = blockIdx.x * 128, n0 = blockIdx.y * 128;

    // staging assignment: this wave loads plane=wave (0..3), both row-halves, A and B.
    const int plane = wave;
    const bf16_t* gA0 = A  + (size_t)(m0 + lane)      * K + plane * 8;
    const bf16_t* gA1 = A  + (size_t)(m0 + 64 + lane) * K + plane * 8;
    const bf16_t* gB0 = BT + (size_t)(n0 + lane)      * K + plane * 8;
    const bf16_t* gB1 = BT + (size_t)(n0 + 64 + lane) * K + plane * 8;
    bf16_t* lA0 = &As[(plane * 128 +  0) * 8];
    bf16_t* lA1 = &As[(plane * 128 + 64) * 8];
    bf16_t* lB0 = &Bs[(plane * 128 +  0) * 8];
    bf16_t* lB1 = &Bs[(plane * 128 + 64) * 8];

    f32x4 acc[4][4];
    #pragma unroll
    for (int mt = 0; mt < 4; mt++)
        #pragma unroll
        for (int nt = 0; nt < 4; nt++)
            acc[mt][nt] = (f32x4)(0.0f);

    for (int k0 = 0; k0 < K; k0 += 32) {
        load16(gA0 + k0, lA0);
        load16(gA1 + k0, lA1);
        load16(gB0 + k0, lB0);
        load16(gB1 + k0, lB1);
        __syncthreads();
        bf16x8 af[4], bfr[4];
        #pragma unroll
        for (int t = 0; t < 4; t++) {
            af[t]  = *reinterpret_cast<const bf16x8*>(&As[(q * 128 + wm * 64 + t * 16 + lrow) * 8]);
            bfr[t] = *reinterpret_cast<const bf16x8*>(&Bs[(q * 128 + wn * 64 + t * 16 + lrow) * 8]);
        }
        #pragma unroll
        for (int mt = 0; mt < 4; mt++)
            #pragma unroll
            for (int nt = 0; nt < 4; nt++)
                acc[mt][nt] = __builtin_amdgcn_mfma_f32_16x16x32_bf16(af[mt], bfr[nt], acc[mt][nt], 0, 0, 0);
        __syncthreads();
    }

    int colg[4]; float bias_v[4];
    #pragma unroll
    for (int nt = 0; nt < 4; nt++) {
        colg[nt] = n0 + wn * 64 + nt * 16 + lrow;
        bias_v[nt] = (colg[nt] < realN) ? bias[colg[nt]] : 0.0f;
    }

    if constexpr (LSE) {
        #pragma unroll
        for (int mt = 0; mt < 4; mt++) {
            int rowb = m0 + wm * 64 + mt * 16 + q * 4;
            #pragma unroll
            for (int r = 0; r < 4; r++) {
                int tok = rowb + r;
                int tg  = tgt[tok];
                float s = 0.0f;
                #pragma unroll
                for (int nt = 0; nt < 4; nt++) {
                    if (colg[nt] < realN) {
                        float logit = acc[mt][nt][r] + bias_v[nt];
                        s += __expf(logit);
                        if (colg[nt] == tg) atomicAdd(&lab[tok], logit);
                    }
                }
                s += __shfl_xor(s, 1);
                s += __shfl_xor(s, 2);
                s += __shfl_xor(s, 4);
                s += __shfl_xor(s, 8);
                if (lrow == 0) atomicAdd(&sumexp[tok], s);
            }
        }
    } else {
        #pragma unroll
        for (int mt = 0; mt < 4; mt++) {
            int rowb = m0 + wm * 64 + mt * 16 + q * 4;
            #pragma unroll
            for (int r = 0; r < 4; r++) {
                int tok = rowb + r;
                #pragma unroll
                for (int nt = 0; nt < 4; nt++)
                    out[(size_t)tok * Npad + colg[nt]] = (bf16_t)(acc[mt][nt][r] + bias_v[nt]);
            }
        }
    }
}

// ---------------- finalize: per-token loss, mask, mean ----------------
__global__ void finalize_kernel(const int* __restrict__ labels, const float* __restrict__ acc6,
                                float* __restrict__ out) {
    int t = blockIdx.x * blockDim.x + threadIdx.x;   // 4096 threads
    const float* sumH = acc6;
    const float* labH = acc6 + M_TOK;
    const float* sum0 = acc6 + 2 * M_TOK;
    const float* lab0 = acc6 + 3 * M_TOK;
    const float* sum1 = acc6 + 4 * M_TOK;
    const float* lab1 = acc6 + 5 * M_TOK;
    int lbl = labels[t];
    float l = 0.0f;
    if (lbl != 0) {
        l = logf(sumH[t]) - labH[t];
        if (lbl >= 16000 && lbl < 28000) l += logf(sum0[t]) - lab0[t];
        else if (lbl >= 28000)           l += logf(sum1[t]) - lab1[t];
    }
    l *= (1.0f / (float)M_TOK);
    #pragma unroll
    for (int off = 1; off < 64; off <<= 1) l += __shfl_xor(l, off);
    __shared__ float red[4];
    if ((threadIdx.x & 63) == 0) red[threadIdx.x >> 6] = l;
    __syncthreads();
    if (threadIdx.x == 0) atomicAdd(out, red[0] + red[1] + red[2] + red[3]);
}

// ---------------- host launcher ----------------
extern "C" void kernel_launch(void* const* d_in, const int* in_sizes, int n_in,
                              void* d_out, int out_size, void* d_ws, size_t ws_size,
                              hipStream_t stream) {
    const float* inp    = (const float*)d_in[0];
    const int*   labels = (const int*)  d_in[1];
    const float* head_W = (const float*)d_in[2];
    const float* head_b = (const float*)d_in[3];
    const float* t0_pW  = (const float*)d_in[4];
    const float* t0_pb  = (const float*)d_in[5];
    const float* t0_W   = (const float*)d_in[6];
    const float* t0_b   = (const float*)d_in[7];
    const float* t1_pW  = (const float*)d_in[8];
    const float* t1_pb  = (const float*)d_in[9];
    const float* t1_W   = (const float*)d_in[10];
    const float* t1_b   = (const float*)d_in[11];
    float* out = (float*)d_out;

    char* ws = (char*)d_ws;
    size_t off = 0;
    auto alloc = [&](size_t bytes) { char* p = ws + off; off += (bytes + 255) & ~(size_t)255; return p; };
    bf16_t* inp_bf = (bf16_t*)alloc((size_t)M_TOK * HID * 2);
    bf16_t* headWT = (bf16_t*)alloc((size_t)NHEAD_PAD * HID * 2);
    bf16_t* p0WT   = (bf16_t*)alloc((size_t)P0 * HID * 2);
    bf16_t* p1WT   = (bf16_t*)alloc((size_t)P1_PAD * HID * 2);
    bf16_t* t0WT   = (bf16_t*)alloc((size_t)N0_PAD * P0 * 2);
    bf16_t* t1WT   = (bf16_t*)alloc((size_t)N1_PAD * P1_PAD * 2);
    bf16_t* proj0  = (bf16_t*)alloc((size_t)M_TOK * P0 * 2);
    bf16_t* proj1  = (bf16_t*)alloc((size_t)M_TOK * P1_PAD * 2);
    float*  acc6   = (float*) alloc(6 * M_TOK * 4);
    int*    tgts   = (int*)   alloc(3 * M_TOK * 4);

    // stage 1: conversions / transposes
    cast_kernel<<<(M_TOK * HID / 4 + 255) / 256, 256, 0, stream>>>(inp, inp_bf, M_TOK * HID / 4);
    transpose_pad<<<dim3(NHEAD_PAD / 32, HID / 64),    256, 0, stream>>>(head_W, headWT, HID, NHEAD, HID,    NHEAD_PAD);
    transpose_pad<<<dim3(P0 / 32,        HID / 64),    256, 0, stream>>>(t0_pW,  p0WT,   HID, P0,    HID,    P0);
    transpose_pad<<<dim3(P1_PAD / 32,    HID / 64),    256, 0, stream>>>(t1_pW,  p1WT,   HID, P1,    HID,    P1_PAD);
    transpose_pad<<<dim3(N0_PAD / 32,    P0 / 64),     256, 0, stream>>>(t0_W,   t0WT,   P0,  N0,    P0,     N0_PAD);
    transpose_pad<<<dim3(N1_PAD / 32,    P1_PAD / 64), 256, 0, stream>>>(t1_W,   t1WT,   P1,  N1,    P1_PAD, N1_PAD);
    init_kernel<<<M_TOK / 256, 256, 0, stream>>>(labels, acc6, tgts, out);

    // stage 2: tail projections (store epilogue)
    gemm_kernel<false><<<dim3(M_TOK / 128, P0 / 128),     256, 0, stream>>>(inp_bf, p0WT, t0_pb, HID, P0,     P0, nullptr, nullptr, nullptr, proj0);
    gemm_kernel<false><<<dim3(M_TOK / 128, P1_PAD / 128), 256, 0, stream>>>(inp_bf, p1WT, t1_pb, HID, P1_PAD, P1, nullptr, nullptr, nullptr, proj1);

    // stage 3: logsumexp GEMMs (head + tails)
    gemm_kernel<true><<<dim3(M_TOK / 128, NHEAD_PAD / 128), 256, 0, stream>>>(inp_bf, headWT, head_b, HID,    NHEAD_PAD, NHEAD, tgts,             acc6,             acc6 + M_TOK,     nullptr);
    gemm_kernel<true><<<dim3(M_TOK / 128, N0_PAD / 128),    256, 0, stream>>>(proj0,  t0WT,   t0_b,   P0,     N0_PAD,    N0,    tgts + M_TOK,     acc6 + 2 * M_TOK, acc6 + 3 * M_TOK, nullptr);
    gemm_kernel<true><<<dim3(M_TOK / 128, N1_PAD / 128),    256, 0, stream>>>(proj1,  t1WT,   t1_b,   P1_PAD, N1_PAD,    N1,    tgts + 2 * M_TOK, acc6 + 4 * M_TOK, acc6 + 5 * M_TOK, nullptr);

    // stage 4: reduce to scalar mean
    finalize_kernel<<<M_TOK / 256, 256, 0, stream>>>(labels, acc6, out);
}

// Round 4
// 487.586 us; speedup vs baseline: 1.2615x; 1.2615x over previous
//
#include <hip/hip_runtime.h>
#include <hip/hip_bf16.h>
#include <cstdint>
#include <cstddef>

// ---------------- problem constants ----------------
#define M_TOK 4096          // B*S = 4*1024 tokens
#define HID   1024
#define NHEAD 16002
#define NHEAD_PAD 16128     // 126*128
#define P0    256
#define N0    12000
#define N0_PAD 12032        // 94*128
#define P1    64
#define P1_PAD 128
#define N1    8000
#define N1_PAD 8064         // 63*128

typedef __bf16 bf16_t;
typedef __bf16 bf16x8 __attribute__((ext_vector_type(8)));
typedef __bf16 bf16x4 __attribute__((ext_vector_type(4)));
typedef float  f32x4  __attribute__((ext_vector_type(4)));

// async global->LDS, 16B per lane. lds ptr must be wave-uniform base;
// HW writes base + lane*16 (m104/m108 semantics).
__device__ __forceinline__ void load16(const bf16_t* g, bf16_t* l) {
    __builtin_amdgcn_global_load_lds(
        (__attribute__((address_space(1))) void*)g,
        (__attribute__((address_space(3))) void*)l,
        16, 0, 0);
}

// ---------------- cast inp f32 -> bf16 (vectorized x4) ----------------
__global__ void cast_kernel(const float* __restrict__ src, bf16_t* __restrict__ dst, int n4) {
    int i = blockIdx.x * blockDim.x + threadIdx.x;
    if (i < n4) {
        float4 v = reinterpret_cast<const float4*>(src)[i];
        bf16x4 o;
        o[0] = (bf16_t)v.x; o[1] = (bf16_t)v.y; o[2] = (bf16_t)v.z; o[3] = (bf16_t)v.w;
        reinterpret_cast<bf16x4*>(dst)[i] = o;
    }
}

// ---------------- tiled transpose with zero padding ----------------
__global__ void transpose_pad(const float* __restrict__ W, bf16_t* __restrict__ WT,
                              int K, int N, int Kpad, int Npad) {
    __shared__ float tile[64][33];
    int n0 = blockIdx.x * 32, k0 = blockIdx.y * 64;
    int tx = threadIdx.x & 31, ty = threadIdx.x >> 5;   // 32 x 8
    #pragma unroll
    for (int i = 0; i < 8; i++) {
        int k = k0 + ty + i * 8, n = n0 + tx;
        tile[ty + i * 8][tx] = (k < K && n < N) ? W[(size_t)k * N + n] : 0.0f;
    }
    __syncthreads();
    int n = threadIdx.x >> 3, kc = threadIdx.x & 7;     // n 0..31, kc 0..7
    bf16x8 v;
    #pragma unroll
    for (int j = 0; j < 8; j++) v[j] = (bf16_t)tile[kc * 8 + j][n];
    *reinterpret_cast<bf16x8*>(WT + (size_t)(n0 + n) * Kpad + k0 + kc * 8) = v;
}

// ---------------- init: zero accumulators + out, precompute targets ----------------
__global__ void init_kernel(const int* __restrict__ labels, float* __restrict__ acc6,
                            int* __restrict__ tgts, float* __restrict__ out) {
    int t = blockIdx.x * blockDim.x + threadIdx.x;   // 4096 threads
    for (int j = t; j < 6 * M_TOK; j += M_TOK) acc6[j] = 0.0f;
    if (t == 0) out[0] = 0.0f;
    int lbl = labels[t];
    tgts[t]             = (lbl < 16000) ? lbl : ((lbl < 28000) ? 16000 : 16001);
    int t0 = lbl - 16000; t0 = t0 < 0 ? 0 : (t0 > 11999 ? 11999 : t0);
    int t1 = lbl - 28000; t1 = t1 < 0 ? 0 : (t1 > 7999  ? 7999  : t1);
    tgts[M_TOK + t]     = t0;
    tgts[2 * M_TOK + t] = t1;
}

// ---------------- MFMA GEMM: C = A(M x K) * BT(Npad x K)^T ----------------
// Block tile 128x128, BK=32, 4 waves 2x2, each wave 64x64 via 4x4 mfma_f32_16x16x32_bf16.
// Staging = R2's coalesced global_load_lds (4 lanes per 64B row), but with the low-2
// granule bits XOR-swizzled (cp) so the LDS arrangement is conflict-free on the
// fragment ds_read_b128 side: read granule = row*4 + (q ^ ((row>>1)&3)) ->
// per 16-lane phase, 8 distinct bank-groups x2 = 2-way = free (m136).
template <bool LSE>
__launch_bounds__(256, 2)
__global__ void gemm_kernel(const bf16_t* __restrict__ A, const bf16_t* __restrict__ BT,
                            const float* __restrict__ bias, int K, int Npad, int realN,
                            const int* __restrict__ tgt, float* __restrict__ sumexp,
                            float* __restrict__ lab, bf16_t* __restrict__ out) {
    __shared__ __align__(16) bf16_t As[128 * 32];
    __shared__ __align__(16) bf16_t Bs[128 * 32];

    const int tid  = threadIdx.x;
    const int lane = tid & 63;
    const int wave = tid >> 6;
    const int wm = wave >> 1, wn = wave & 1;
    const int q = lane >> 4, lrow = lane & 15;
    const int m0 = blockIdx.x * 128, n0 = blockIdx.y * 128;

    // staging: lane c in chunk; permute low 2 granule bits for swizzled LDS layout.
    // global row/ko derived from permuted index cp; coalescing unchanged (same 64B rows).
    int gofs[2];  // element offset within tile (row*K + ko), per p
    #pragma unroll
    for (int p = 0; p < 2; p++) {
        int c  = wave * 64 + p * 256 + lane;
        int cp = (c & ~3) | ((c & 3) ^ ((c >> 3) & 3));
        gofs[p] = (cp >> 2) * K + (cp & 3) * 8;
    }
    const int base0 = (wave * 64 + 0 * 256) * 8;   // LDS element offset, wave-uniform
    const int base1 = (wave * 64 + 1 * 256) * 8;

    f32x4 acc[4][4];
    #pragma unroll
    for (int mt = 0; mt < 4; mt++)
        #pragma unroll
        for (int nt = 0; nt < 4; nt++)
            acc[mt][nt] = (f32x4)(0.0f);

    const bf16_t* Abase = A  + (size_t)m0 * K;
    const bf16_t* Bbase = BT + (size_t)n0 * K;

    for (int k0 = 0; k0 < K; k0 += 32) {
        load16(Abase + k0 + gofs[0], &As[0] + base0);
        load16(Abase + k0 + gofs[1], &As[0] + base1);
        load16(Bbase + k0 + gofs[0], &Bs[0] + base0);
        load16(Bbase + k0 + gofs[1], &Bs[0] + base1);
        __syncthreads();
        bf16x8 af[4], bfr[4];
        #pragma unroll
        for (int t = 0; t < 4; t++) {
            int rA = wm * 64 + t * 16 + lrow;
            int rB = wn * 64 + t * 16 + lrow;
            int sw = q ^ ((lrow >> 1) & 3);
            af[t]  = *reinterpret_cast<const bf16x8*>(&As[(rA * 4 + sw) * 8]);
            bfr[t] = *reinterpret_cast<const bf16x8*>(&Bs[(rB * 4 + sw) * 8]);
        }
        #pragma unroll
        for (int mt = 0; mt < 4; mt++)
            #pragma unroll
            for (int nt = 0; nt < 4; nt++)
                acc[mt][nt] = __builtin_amdgcn_mfma_f32_16x16x32_bf16(af[mt], bfr[nt], acc[mt][nt], 0, 0, 0);
        __syncthreads();
    }

    int colg[4]; float bias_v[4];
    #pragma unroll
    for (int nt = 0; nt < 4; nt++) {
        colg[nt] = n0 + wn * 64 + nt * 16 + lrow;
        bias_v[nt] = (colg[nt] < realN) ? bias[colg[nt]] : 0.0f;
    }

    if constexpr (LSE) {
        #pragma unroll
        for (int mt = 0; mt < 4; mt++) {
            int rowb = m0 + wm * 64 + mt * 16 + q * 4;
            #pragma unroll
            for (int r = 0; r < 4; r++) {
                int tok = rowb + r;
                int tg  = tgt[tok];
                float s = 0.0f;
                #pragma unroll
                for (int nt = 0; nt < 4; nt++) {
                    if (colg[nt] < realN) {
                        float logit = acc[mt][nt][r] + bias_v[nt];
                        s += __expf(logit);
                        if (colg[nt] == tg) atomicAdd(&lab[tok], logit);
                    }
                }
                s += __shfl_xor(s, 1);
                s += __shfl_xor(s, 2);
                s += __shfl_xor(s, 4);
                s += __shfl_xor(s, 8);
                if (lrow == 0) atomicAdd(&sumexp[tok], s);
            }
        }
    } else {
        #pragma unroll
        for (int mt = 0; mt < 4; mt++) {
            int rowb = m0 + wm * 64 + mt * 16 + q * 4;
            #pragma unroll
            for (int r = 0; r < 4; r++) {
                int tok = rowb + r;
                #pragma unroll
                for (int nt = 0; nt < 4; nt++)
                    out[(size_t)tok * Npad + colg[nt]] = (bf16_t)(acc[mt][nt][r] + bias_v[nt]);
            }
        }
    }
}

// ---------------- finalize: per-token loss, mask, mean ----------------
__global__ void finalize_kernel(const int* __restrict__ labels, const float* __restrict__ acc6,
                                float* __restrict__ out) {
    int t = blockIdx.x * blockDim.x + threadIdx.x;   // 4096 threads
    const float* sumH = acc6;
    const float* labH = acc6 + M_TOK;
    const float* sum0 = acc6 + 2 * M_TOK;
    const float* lab0 = acc6 + 3 * M_TOK;
    const float* sum1 = acc6 + 4 * M_TOK;
    const float* lab1 = acc6 + 5 * M_TOK;
    int lbl = labels[t];
    float l = 0.0f;
    if (lbl != 0) {
        l = logf(sumH[t]) - labH[t];
        if (lbl >= 16000 && lbl < 28000) l += logf(sum0[t]) - lab0[t];
        else if (lbl >= 28000)           l += logf(sum1[t]) - lab1[t];
    }
    l *= (1.0f / (float)M_TOK);
    #pragma unroll
    for (int off = 1; off < 64; off <<= 1) l += __shfl_xor(l, off);
    __shared__ float red[4];
    if ((threadIdx.x & 63) == 0) red[threadIdx.x >> 6] = l;
    __syncthreads();
    if (threadIdx.x == 0) atomicAdd(out, red[0] + red[1] + red[2] + red[3]);
}

// ---------------- host launcher ----------------
extern "C" void kernel_launch(void* const* d_in, const int* in_sizes, int n_in,
                              void* d_out, int out_size, void* d_ws, size_t ws_size,
                              hipStream_t stream) {
    const float* inp    = (const float*)d_in[0];
    const int*   labels = (const int*)  d_in[1];
    const float* head_W = (const float*)d_in[2];
    const float* head_b = (const float*)d_in[3];
    const float* t0_pW  = (const float*)d_in[4];
    const float* t0_pb  = (const float*)d_in[5];
    const float* t0_W   = (const float*)d_in[6];
    const float* t0_b   = (const float*)d_in[7];
    const float* t1_pW  = (const float*)d_in[8];
    const float* t1_pb  = (const float*)d_in[9];
    const float* t1_W   = (const float*)d_in[10];
    const float* t1_b   = (const float*)d_in[11];
    float* out = (float*)d_out;

    char* ws = (char*)d_ws;
    size_t off = 0;
    auto alloc = [&](size_t bytes) { char* p = ws + off; off += (bytes + 255) & ~(size_t)255; return p; };
    bf16_t* inp_bf = (bf16_t*)alloc((size_t)M_TOK * HID * 2);
    bf16_t* headWT = (bf16_t*)alloc((size_t)NHEAD_PAD * HID * 2);
    bf16_t* p0WT   = (bf16_t*)alloc((size_t)P0 * HID * 2);
    bf16_t* p1WT   = (bf16_t*)alloc((size_t)P1_PAD * HID * 2);
    bf16_t* t0WT   = (bf16_t*)alloc((size_t)N0_PAD * P0 * 2);
    bf16_t* t1WT   = (bf16_t*)alloc((size_t)N1_PAD * P1_PAD * 2);
    bf16_t* proj0  = (bf16_t*)alloc((size_t)M_TOK * P0 * 2);
    bf16_t* proj1  = (bf16_t*)alloc((size_t)M_TOK * P1_PAD * 2);
    float*  acc6   = (float*) alloc(6 * M_TOK * 4);
    int*    tgts   = (int*)   alloc(3 * M_TOK * 4);

    // stage 1: conversions / transposes
    cast_kernel<<<(M_TOK * HID / 4 + 255) / 256, 256, 0, stream>>>(inp, inp_bf, M_TOK * HID / 4);
    transpose_pad<<<dim3(NHEAD_PAD / 32, HID / 64),    256, 0, stream>>>(head_W, headWT, HID, NHEAD, HID,    NHEAD_PAD);
    transpose_pad<<<dim3(P0 / 32,        HID / 64),    256, 0, stream>>>(t0_pW,  p0WT,   HID, P0,    HID,    P0);
    transpose_pad<<<dim3(P1_PAD / 32,    HID / 64),    256, 0, stream>>>(t1_pW,  p1WT,   HID, P1,    HID,    P1_PAD);
    transpose_pad<<<dim3(N0_PAD / 32,    P0 / 64),     256, 0, stream>>>(t0_W,   t0WT,   P0,  N0,    P0,     N0_PAD);
    transpose_pad<<<dim3(N1_PAD / 32,    P1_PAD / 64), 256, 0, stream>>>(t1_W,   t1WT,   P1,  N1,    P1_PAD, N1_PAD);
    init_kernel<<<M_TOK / 256, 256, 0, stream>>>(labels, acc6, tgts, out);

    // stage 2: tail projections (store epilogue)
    gemm_kernel<false><<<dim3(M_TOK / 128, P0 / 128),     256, 0, stream>>>(inp_bf, p0WT, t0_pb, HID, P0,     P0, nullptr, nullptr, nullptr, proj0);
    gemm_kernel<false><<<dim3(M_TOK / 128, P1_PAD / 128), 256, 0, stream>>>(inp_bf, p1WT, t1_pb, HID, P1_PAD, P1, nullptr, nullptr, nullptr, proj1);

    // stage 3: logsumexp GEMMs (head + tails)
    gemm_kernel<true><<<dim3(M_TOK / 128, NHEAD_PAD / 128), 256, 0, stream>>>(inp_bf, headWT, head_b, HID,    NHEAD_PAD, NHEAD, tgts,             acc6,             acc6 + M_TOK,     nullptr);
    gemm_kernel<true><<<dim3(M_TOK / 128, N0_PAD / 128),    256, 0, stream>>>(proj0,  t0WT,   t0_b,   P0,     N0_PAD,    N0,    tgts + M_TOK,     acc6 + 2 * M_TOK, acc6 + 3 * M_TOK, nullptr);
    gemm_kernel<true><<<dim3(M_TOK / 128, N1_PAD / 128),    256, 0, stream>>>(proj1,  t1WT,   t1_b,   P1_PAD, N1_PAD,    N1,    tgts + 2 * M_TOK, acc6 + 4 * M_TOK, acc6 + 5 * M_TOK, nullptr);

    // stage 4: reduce to scalar mean
    finalize_kernel<<<M_TOK / 256, 256, 0, stream>>>(labels, acc6, out);
}

// Round 5
// 429.361 us; speedup vs baseline: 1.4326x; 1.1356x over previous
//
#include <hip/hip_runtime.h>
#include <hip/hip_bf16.h>
#include <hip/hip_fp8.h>
#include <cstdint>
#include <cstddef>

// ---------------- problem constants ----------------
#define M_TOK 4096          // B*S = 4*1024 tokens
#define HID   1024
#define NHEAD 16002
#define NHEAD_PAD 16128     // 126*128
#define P0    256
#define N0    12000
#define N0_PAD 12032        // 94*128
#define P1    64
#define P1_PAD 128
#define N1    8000
#define N1_PAD 8064         // 63*128

typedef __bf16 bf16_t;
typedef unsigned char u8;
typedef __bf16 bf16x8 __attribute__((ext_vector_type(8)));
typedef __bf16 bf16x4 __attribute__((ext_vector_type(4)));
typedef float  f32x4  __attribute__((ext_vector_type(4)));
typedef int    i32x4  __attribute__((ext_vector_type(4)));
typedef int    i32x8  __attribute__((ext_vector_type(8)));

// async global->LDS, 16B per lane. lds ptr must be wave-uniform base;
// HW writes base + lane*16 (m104/m108 semantics).
__device__ __forceinline__ void load16(const void* g, void* l) {
    __builtin_amdgcn_global_load_lds(
        (__attribute__((address_space(1))) void*)g,
        (__attribute__((address_space(3))) void*)l,
        16, 0, 0);
}

__device__ __forceinline__ u8 to_e4m3(float f) {
    __hip_fp8_e4m3 h(f);
    return (u8)h.__x;
}

// ---------------- cast inp f32 -> bf16 + fp8 e4m3 ----------------
__global__ void cast_kernel(const float* __restrict__ src, bf16_t* __restrict__ dst,
                            u8* __restrict__ dst8, int n4) {
    int i = blockIdx.x * blockDim.x + threadIdx.x;
    if (i < n4) {
        float4 v = reinterpret_cast<const float4*>(src)[i];
        bf16x4 o;
        o[0] = (bf16_t)v.x; o[1] = (bf16_t)v.y; o[2] = (bf16_t)v.z; o[3] = (bf16_t)v.w;
        reinterpret_cast<bf16x4*>(dst)[i] = o;
        uchar4 o8;
        o8.x = to_e4m3(v.x); o8.y = to_e4m3(v.y); o8.z = to_e4m3(v.z); o8.w = to_e4m3(v.w);
        reinterpret_cast<uchar4*>(dst8)[i] = o8;
    }
}

// ---------------- tiled transpose with zero padding (bf16 out) ----------------
__global__ void transpose_pad(const float* __restrict__ W, bf16_t* __restrict__ WT,
                              int K, int N, int Kpad, int Npad) {
    __shared__ float tile[64][33];
    int n0 = blockIdx.x * 32, k0 = blockIdx.y * 64;
    int tx = threadIdx.x & 31, ty = threadIdx.x >> 5;   // 32 x 8
    #pragma unroll
    for (int i = 0; i < 8; i++) {
        int k = k0 + ty + i * 8, n = n0 + tx;
        tile[ty + i * 8][tx] = (k < K && n < N) ? W[(size_t)k * N + n] : 0.0f;
    }
    __syncthreads();
    int n = threadIdx.x >> 3, kc = threadIdx.x & 7;     // n 0..31, kc 0..7
    bf16x8 v;
    #pragma unroll
    for (int j = 0; j < 8; j++) v[j] = (bf16_t)tile[kc * 8 + j][n];
    *reinterpret_cast<bf16x8*>(WT + (size_t)(n0 + n) * Kpad + k0 + kc * 8) = v;
}

// ---------------- tiled transpose: f32 -> fp8 e4m3, pre-scaled ----------------
__global__ void transpose_pad_fp8(const float* __restrict__ W, u8* __restrict__ WT,
                                  int K, int N, int Kpad, float scale) {
    __shared__ float tile[64][33];
    int n0 = blockIdx.x * 32, k0 = blockIdx.y * 64;
    int tx = threadIdx.x & 31, ty = threadIdx.x >> 5;   // 32 x 8
    #pragma unroll
    for (int i = 0; i < 8; i++) {
        int k = k0 + ty + i * 8, n = n0 + tx;
        tile[ty + i * 8][tx] = (k < K && n < N) ? W[(size_t)k * N + n] * scale : 0.0f;
    }
    __syncthreads();
    int n = threadIdx.x >> 3, kc = threadIdx.x & 7;     // n 0..31, kc 0..7
    union { u8 b[8]; uint2 u; } v;
    #pragma unroll
    for (int j = 0; j < 8; j++) v.b[j] = to_e4m3(tile[kc * 8 + j][n]);
    *reinterpret_cast<uint2*>(WT + (size_t)(n0 + n) * Kpad + k0 + kc * 8) = v.u;
}

// ---------------- init: zero accumulators + out, precompute targets ----------------
__global__ void init_kernel(const int* __restrict__ labels, float* __restrict__ acc6,
                            int* __restrict__ tgts, float* __restrict__ out) {
    int t = blockIdx.x * blockDim.x + threadIdx.x;   // 4096 threads
    for (int j = t; j < 6 * M_TOK; j += M_TOK) acc6[j] = 0.0f;
    if (t == 0) out[0] = 0.0f;
    int lbl = labels[t];
    tgts[t]             = (lbl < 16000) ? lbl : ((lbl < 28000) ? 16000 : 16001);
    int t0 = lbl - 16000; t0 = t0 < 0 ? 0 : (t0 > 11999 ? 11999 : t0);
    int t1 = lbl - 28000; t1 = t1 < 0 ? 0 : (t1 > 7999  ? 7999  : t1);
    tgts[M_TOK + t]     = t0;
    tgts[2 * M_TOK + t] = t1;
}

// ---------------- MX-fp8 head GEMM + LSE epilogue ----------------
// C = A(M x K fp8) * BT(NPAD x K fp8, pre-scaled x32)^T, via
// mfma_scale_f32_16x16x128_f8f6f4 (A-scale 1.0, B-scale 2^-5).
// Block 128x128, BK=128, 4 waves 2x2, each wave 64x64 via 4x4 MFMAs.
// LDS: granule(16B) p stored at p*16; p = row*8 + (gcol ^ (row&7)) [XOR swizzle]
// -> fragment ds_read_b128: every 8-lane phase covers all 8 bank-groups, 0 conflicts.
__launch_bounds__(256, 2)
__global__ void gemm_fp8_lse(const u8* __restrict__ A, const u8* __restrict__ BT,
                             const float* __restrict__ bias, int K, int realN,
                             const int* __restrict__ tgt, float* __restrict__ sumexp,
                             float* __restrict__ lab) {
    __shared__ __align__(16) u8 As[128 * 128];
    __shared__ __align__(16) u8 Bs[128 * 128];

    const int tid  = threadIdx.x;
    const int lane = tid & 63;
    const int wave = tid >> 6;
    const int wm = wave >> 1, wn = wave & 1;
    const int q = lane >> 4, lrow = lane & 15;
    const int m0 = blockIdx.x * 128, n0 = blockIdx.y * 128;

    // staging: physical granule g = wave*256 + p*64 + lane, p=0..3 (1024 granules total)
    // logical: row = g>>3, gcol = (g&7) ^ (row&7); global byte = row*K + gcol*16
    int gofs[4];
    #pragma unroll
    for (int p = 0; p < 4; p++) {
        int g = wave * 256 + p * 64 + lane;
        int row = g >> 3, gcol = (g & 7) ^ (row & 7);
        gofs[p] = row * K + gcol * 16;
    }

    f32x4 acc[4][4];
    #pragma unroll
    for (int mt = 0; mt < 4; mt++)
        #pragma unroll
        for (int nt = 0; nt < 4; nt++)
            acc[mt][nt] = (f32x4)(0.0f);

    const u8* Ab = A  + (size_t)m0 * K;
    const u8* Bb = BT + (size_t)n0 * K;

    union Frag { struct { i32x4 lo, hi; } h; i32x8 v; };

    for (int k0 = 0; k0 < K; k0 += 128) {
        #pragma unroll
        for (int p = 0; p < 4; p++) {
            int base = (wave * 256 + p * 64) * 16;   // wave-uniform LDS byte offset
            load16(Ab + k0 + gofs[p], As + base);
            load16(Bb + k0 + gofs[p], Bs + base);
        }
        __syncthreads();
        Frag fa[4], fb[4];
        #pragma unroll
        for (int t = 0; t < 4; t++) {
            int mA = wm * 64 + t * 16 + lrow;
            int sw = lrow & 7;
            fa[t].h.lo = *reinterpret_cast<const i32x4*>(As + (mA * 8 + ((2 * q)     ^ sw)) * 16);
            fa[t].h.hi = *reinterpret_cast<const i32x4*>(As + (mA * 8 + ((2 * q + 1) ^ sw)) * 16);
            int mB = wn * 64 + t * 16 + lrow;
            fb[t].h.lo = *reinterpret_cast<const i32x4*>(Bs + (mB * 8 + ((2 * q)     ^ sw)) * 16);
            fb[t].h.hi = *reinterpret_cast<const i32x4*>(Bs + (mB * 8 + ((2 * q + 1) ^ sw)) * 16);
        }
        #pragma unroll
        for (int mt = 0; mt < 4; mt++)
            #pragma unroll
            for (int nt = 0; nt < 4; nt++)
                acc[mt][nt] = __builtin_amdgcn_mfma_scale_f32_16x16x128_f8f6f4(
                    fa[mt].v, fb[nt].v, acc[mt][nt],
                    0, 0,                      // cbsz=fp8(e4m3), blgp=fp8(e4m3)
                    0, 0x7F7F7F7F,             // A scale: 2^0 = 1.0 (all bytes)
                    0, 0x7A7A7A7A);            // B scale: 2^-5 = 1/32 (all bytes)
        __syncthreads();
    }

    int colg[4]; float bias_v[4];
    #pragma unroll
    for (int nt = 0; nt < 4; nt++) {
        colg[nt] = n0 + wn * 64 + nt * 16 + lrow;
        bias_v[nt] = (colg[nt] < realN) ? bias[colg[nt]] : 0.0f;
    }

    #pragma unroll
    for (int mt = 0; mt < 4; mt++) {
        int rowb = m0 + wm * 64 + mt * 16 + q * 4;
        #pragma unroll
        for (int r = 0; r < 4; r++) {
            int tok = rowb + r;
            int tg  = tgt[tok];
            float s = 0.0f;
            #pragma unroll
            for (int nt = 0; nt < 4; nt++) {
                if (colg[nt] < realN) {
                    float logit = acc[mt][nt][r] + bias_v[nt];
                    s += __expf(logit);
                    if (colg[nt] == tg) atomicAdd(&lab[tok], logit);
                }
            }
            s += __shfl_xor(s, 1);
            s += __shfl_xor(s, 2);
            s += __shfl_xor(s, 4);
            s += __shfl_xor(s, 8);
            if (lrow == 0) atomicAdd(&sumexp[tok], s);
        }
    }
}

// ---------------- bf16 MFMA GEMM (tails + projections), R4 structure ----------------
template <bool LSE>
__launch_bounds__(256, 2)
__global__ void gemm_kernel(const bf16_t* __restrict__ A, const bf16_t* __restrict__ BT,
                            const float* __restrict__ bias, int K, int Npad, int realN,
                            const int* __restrict__ tgt, float* __restrict__ sumexp,
                            float* __restrict__ lab, bf16_t* __restrict__ out) {
    __shared__ __align__(16) bf16_t As[128 * 32];
    __shared__ __align__(16) bf16_t Bs[128 * 32];

    const int tid  = threadIdx.x;
    const int lane = tid & 63;
    const int wave = tid >> 6;
    const int wm = wave >> 1, wn = wave & 1;
    const int q = lane >> 4, lrow = lane & 15;
    const int m0 = blockIdx.x * 128, n0 = blockIdx.y * 128;

    int gofs[2];
    #pragma unroll
    for (int p = 0; p < 2; p++) {
        int c  = wave * 64 + p * 256 + lane;
        int cp = (c & ~3) | ((c & 3) ^ ((c >> 3) & 3));
        gofs[p] = (cp >> 2) * K + (cp & 3) * 8;
    }
    const int base0 = (wave * 64 + 0 * 256) * 8;
    const int base1 = (wave * 64 + 1 * 256) * 8;

    f32x4 acc[4][4];
    #pragma unroll
    for (int mt = 0; mt < 4; mt++)
        #pragma unroll
        for (int nt = 0; nt < 4; nt++)
            acc[mt][nt] = (f32x4)(0.0f);

    const bf16_t* Abase = A  + (size_t)m0 * K;
    const bf16_t* Bbase = BT + (size_t)n0 * K;

    for (int k0 = 0; k0 < K; k0 += 32) {
        load16(Abase + k0 + gofs[0], &As[0] + base0);
        load16(Abase + k0 + gofs[1], &As[0] + base1);
        load16(Bbase + k0 + gofs[0], &Bs[0] + base0);
        load16(Bbase + k0 + gofs[1], &Bs[0] + base1);
        __syncthreads();
        bf16x8 af[4], bfr[4];
        #pragma unroll
        for (int t = 0; t < 4; t++) {
            int rA = wm * 64 + t * 16 + lrow;
            int rB = wn * 64 + t * 16 + lrow;
            int sw = q ^ ((lrow >> 1) & 3);
            af[t]  = *reinterpret_cast<const bf16x8*>(&As[(rA * 4 + sw) * 8]);
            bfr[t] = *reinterpret_cast<const bf16x8*>(&Bs[(rB * 4 + sw) * 8]);
        }
        #pragma unroll
        for (int mt = 0; mt < 4; mt++)
            #pragma unroll
            for (int nt = 0; nt < 4; nt++)
                acc[mt][nt] = __builtin_amdgcn_mfma_f32_16x16x32_bf16(af[mt], bfr[nt], acc[mt][nt], 0, 0, 0);
        __syncthreads();
    }

    int colg[4]; float bias_v[4];
    #pragma unroll
    for (int nt = 0; nt < 4; nt++) {
        colg[nt] = n0 + wn * 64 + nt * 16 + lrow;
        bias_v[nt] = (colg[nt] < realN) ? bias[colg[nt]] : 0.0f;
    }

    if constexpr (LSE) {
        #pragma unroll
        for (int mt = 0; mt < 4; mt++) {
            int rowb = m0 + wm * 64 + mt * 16 + q * 4;
            #pragma unroll
            for (int r = 0; r < 4; r++) {
                int tok = rowb + r;
                int tg  = tgt[tok];
                float s = 0.0f;
                #pragma unroll
                for (int nt = 0; nt < 4; nt++) {
                    if (colg[nt] < realN) {
                        float logit = acc[mt][nt][r] + bias_v[nt];
                        s += __expf(logit);
                        if (colg[nt] == tg) atomicAdd(&lab[tok], logit);
                    }
                }
                s += __shfl_xor(s, 1);
                s += __shfl_xor(s, 2);
                s += __shfl_xor(s, 4);
                s += __shfl_xor(s, 8);
                if (lrow == 0) atomicAdd(&sumexp[tok], s);
            }
        }
    } else {
        #pragma unroll
        for (int mt = 0; mt < 4; mt++) {
            int rowb = m0 + wm * 64 + mt * 16 + q * 4;
            #pragma unroll
            for (int r = 0; r < 4; r++) {
                int tok = rowb + r;
                #pragma unroll
                for (int nt = 0; nt < 4; nt++)
                    out[(size_t)tok * Npad + colg[nt]] = (bf16_t)(acc[mt][nt][r] + bias_v[nt]);
            }
        }
    }
}

// ---------------- finalize: per-token loss, mask, mean ----------------
__global__ void finalize_kernel(const int* __restrict__ labels, const float* __restrict__ acc6,
                                float* __restrict__ out) {
    int t = blockIdx.x * blockDim.x + threadIdx.x;   // 4096 threads
    const float* sumH = acc6;
    const float* labH = acc6 + M_TOK;
    const float* sum0 = acc6 + 2 * M_TOK;
    const float* lab0 = acc6 + 3 * M_TOK;
    const float* sum1 = acc6 + 4 * M_TOK;
    const float* lab1 = acc6 + 5 * M_TOK;
    int lbl = labels[t];
    float l = 0.0f;
    if (lbl != 0) {
        l = logf(sumH[t]) - labH[t];
        if (lbl >= 16000 && lbl < 28000) l += logf(sum0[t]) - lab0[t];
        else if (lbl >= 28000)           l += logf(sum1[t]) - lab1[t];
    }
    l *= (1.0f / (float)M_TOK);
    #pragma unroll
    for (int off = 1; off < 64; off <<= 1) l += __shfl_xor(l, off);
    __shared__ float red[4];
    if ((threadIdx.x & 63) == 0) red[threadIdx.x >> 6] = l;
    __syncthreads();
    if (threadIdx.x == 0) atomicAdd(out, red[0] + red[1] + red[2] + red[3]);
}

// ---------------- host launcher ----------------
extern "C" void kernel_launch(void* const* d_in, const int* in_sizes, int n_in,
                              void* d_out, int out_size, void* d_ws, size_t ws_size,
                              hipStream_t stream) {
    const float* inp    = (const float*)d_in[0];
    const int*   labels = (const int*)  d_in[1];
    const float* head_W = (const float*)d_in[2];
    const float* head_b = (const float*)d_in[3];
    const float* t0_pW  = (const float*)d_in[4];
    const float* t0_pb  = (const float*)d_in[5];
    const float* t0_W   = (const float*)d_in[6];
    const float* t0_b   = (const float*)d_in[7];
    const float* t1_pW  = (const float*)d_in[8];
    const float* t1_pb  = (const float*)d_in[9];
    const float* t1_W   = (const float*)d_in[10];
    const float* t1_b   = (const float*)d_in[11];
    float* out = (float*)d_out;

    char* ws = (char*)d_ws;
    size_t off = 0;
    auto alloc = [&](size_t bytes) { char* p = ws + off; off += (bytes + 255) & ~(size_t)255; return p; };
    bf16_t* inp_bf  = (bf16_t*)alloc((size_t)M_TOK * HID * 2);
    u8*     inp_f8  = (u8*)    alloc((size_t)M_TOK * HID);
    u8*     headWf8 = (u8*)    alloc((size_t)NHEAD_PAD * HID);
    bf16_t* p0WT    = (bf16_t*)alloc((size_t)P0 * HID * 2);
    bf16_t* p1WT    = (bf16_t*)alloc((size_t)P1_PAD * HID * 2);
    bf16_t* t0WT    = (bf16_t*)alloc((size_t)N0_PAD * P0 * 2);
    bf16_t* t1WT    = (bf16_t*)alloc((size_t)N1_PAD * P1_PAD * 2);
    bf16_t* proj0   = (bf16_t*)alloc((size_t)M_TOK * P0 * 2);
    bf16_t* proj1   = (bf16_t*)alloc((size_t)M_TOK * P1_PAD * 2);
    float*  acc6    = (float*) alloc(6 * M_TOK * 4);
    int*    tgts    = (int*)   alloc(3 * M_TOK * 4);

    // stage 1: conversions / transposes
    cast_kernel<<<(M_TOK * HID / 4 + 255) / 256, 256, 0, stream>>>(inp, inp_bf, inp_f8, M_TOK * HID / 4);
    transpose_pad_fp8<<<dim3(NHEAD_PAD / 32, HID / 64), 256, 0, stream>>>(head_W, headWf8, HID, NHEAD, HID, 32.0f);
    transpose_pad<<<dim3(P0 / 32,     HID / 64),    256, 0, stream>>>(t0_pW, p0WT, HID, P0, HID,    P0);
    transpose_pad<<<dim3(P1_PAD / 32, HID / 64),    256, 0, stream>>>(t1_pW, p1WT, HID, P1, HID,    P1_PAD);
    transpose_pad<<<dim3(N0_PAD / 32, P0 / 64),     256, 0, stream>>>(t0_W,  t0WT, P0,  N0, P0,     N0_PAD);
    transpose_pad<<<dim3(N1_PAD / 32, P1_PAD / 64), 256, 0, stream>>>(t1_W,  t1WT, P1,  N1, P1_PAD, N1_PAD);
    init_kernel<<<M_TOK / 256, 256, 0, stream>>>(labels, acc6, tgts, out);

    // stage 2: tail projections (store epilogue, bf16)
    gemm_kernel<false><<<dim3(M_TOK / 128, P0 / 128),     256, 0, stream>>>(inp_bf, p0WT, t0_pb, HID, P0,     P0, nullptr, nullptr, nullptr, proj0);
    gemm_kernel<false><<<dim3(M_TOK / 128, P1_PAD / 128), 256, 0, stream>>>(inp_bf, p1WT, t1_pb, HID, P1_PAD, P1, nullptr, nullptr, nullptr, proj1);

    // stage 3: logsumexp GEMMs — head in MX-fp8, tails in bf16
    gemm_fp8_lse<<<dim3(M_TOK / 128, NHEAD_PAD / 128), 256, 0, stream>>>(inp_f8, headWf8, head_b, HID, NHEAD, tgts, acc6, acc6 + M_TOK);
    gemm_kernel<true><<<dim3(M_TOK / 128, N0_PAD / 128), 256, 0, stream>>>(proj0, t0WT, t0_b, P0,     N0_PAD, N0, tgts + M_TOK,     acc6 + 2 * M_TOK, acc6 + 3 * M_TOK, nullptr);
    gemm_kernel<true><<<dim3(M_TOK / 128, N1_PAD / 128), 256, 0, stream>>>(proj1, t1WT, t1_b, P1_PAD, N1_PAD, N1, tgts + 2 * M_TOK, acc6 + 4 * M_TOK, acc6 + 5 * M_TOK, nullptr);

    // stage 4: reduce to scalar mean
    finalize_kernel<<<M_TOK / 256, 256, 0, stream>>>(labels, acc6, out);
}